// Round 20
// baseline (170.611 us; speedup 1.0000x reference)
//
#include <hip/hip_runtime.h>
#include <math.h>

typedef __attribute__((ext_vector_type(8))) short short8;
typedef __attribute__((ext_vector_type(4))) short short4v;
typedef __attribute__((ext_vector_type(4))) float f32x4;
typedef __attribute__((ext_vector_type(16))) float f32x16;
typedef _Float16 half8 __attribute__((ext_vector_type(8)));

constexpr int BLOCK = 512;
constexpr int B_ = 4, C_ = 64, N_ = 32768, K_ = 16;
constexpr int P_ = 32;            // points per block -> 96 cols (col = k*32 + p)
constexpr int NFRAG = 44;
constexpr int BIAS_OFF = NFRAG * 512;    // shorts

// single-kernel (fallback) x LDS layout
constexpr int ZOFF = 9 * 768;            // 6912
constexpr int XSZ  = 6920;
constexpr int H2STR = 776;

// split-path: x global frag layout = [10 fr][96 col][8] shorts per block
constexpr int XG_SHORTS = 10 * 96 * 8;   // 7680 shorts = 15360 B per block
constexpr size_t XG_OFF = 65536;         // byte offset of x region in d_ws
constexpr int NBLK = B_ * (N_ / P_);     // 4096

__device__ __forceinline__ short f16bits(float v) {
    return (short)__builtin_bit_cast(unsigned short, (_Float16)v);
}
__device__ __forceinline__ f32x16 mm32h(half8 a, half8 b, f32x16 c) {
    return __builtin_amdgcn_mfma_f32_32x32x16_f16(a, b, c, 0, 0, 0);
}
__device__ __forceinline__ f32x4 mm16h(half8 a, half8 b, f32x4 c) {
    return __builtin_amdgcn_mfma_f32_16x16x32_f16(a, b, c, 0, 0, 0);
}

// ---------------- prologue: BN-fold + single-f16 weights + fold biases ------
__global__ void prep_wfrags(const float* __restrict__ W1, const float* __restrict__ g1,
                            const float* __restrict__ b1, const float* __restrict__ be1,
                            const float* __restrict__ W2, const float* __restrict__ g2,
                            const float* __restrict__ b2, const float* __restrict__ be2,
                            const float* __restrict__ W3, const float* __restrict__ g3,
                            const float* __restrict__ b3, const float* __restrict__ be3,
                            unsigned short* __restrict__ wf)
{
    const int gid = blockIdx.x * 256 + threadIdx.x;
    const float RS = 1.0f / sqrtf(1.0f + 1e-5f);
    const int NT = NFRAG * 64;
    if (gid < NT) {
        const int f = gid >> 6, l = gid & 63;
        const float *W, *g; int CI, co, kb;
        if (f < 20)      { W = W1; g = g1; CI = 68;
                           co = (f / 5) * 32 + (l & 31);        kb = (f % 5) * 16 + (l >> 5) * 8; }
        else if (f < 36) { W = W2; g = g2; CI = 128;
                           co = ((f - 20) / 8) * 32 + (l & 31); kb = ((f - 20) % 8) * 16 + (l >> 5) * 8; }
        else             { W = W3; g = g3; CI = 64;
                           co = ((f - 36) / 2) * 16 + (l & 15); kb = ((f - 36) % 2) * 32 + (l >> 4) * 8; }
        const float gs = g[co] * RS;
        short8 h8;
#pragma unroll
        for (int j = 0; j < 8; ++j) {
            const int k = kb + j;
            const float w = (k < CI) ? W[(size_t)co * CI + k] * gs : 0.0f;
            h8[j] = f16bits(w);
        }
        *reinterpret_cast<short8*>(wf + (size_t)f * 512 + l * 8) = h8;
    } else if (gid < NT + 256) {
        const int c = gid - NT;
        float* fb = reinterpret_cast<float*>(wf + BIAS_OFF);
        if (c < 128)      fb[c] = b1[c] * (g1[c] * RS) + be1[c];
        else if (c < 192) { const int q = c - 128; fb[c] = b2[q] * (g2[q] * RS) + be2[q]; }
        else              { const int q = c - 192; fb[c] = b3[q] * (g3[q] * RS) + be3[q]; }
    }
}

__device__ __forceinline__ half8 ldfrag(const unsigned short* __restrict__ wf,
                                        int f, int l) {
    return __builtin_bit_cast(half8,
        *reinterpret_cast<const short8*>(wf + (size_t)f * 512 + l * 8));
}

// ================= K1: compact feat+relation into x-fragment stream =========
__global__ __launch_bounds__(BLOCK, 8)
void prep_x(const float* __restrict__ src, const float* __restrict__ tgt,
            const float* __restrict__ feat, unsigned short* __restrict__ xg)
{
    __shared__ __align__(16) unsigned short xa[XG_SHORTS];   // 15.36 KB

    const int tid = threadIdx.x;
    const int b   = blockIdx.x >> 10;
    const int n0  = (blockIdx.x & 1023) << 5;

    // issue all global loads up front
    float4 pf[4];
#pragma unroll
    for (int it = 0; it < 4; ++it) {
        const int idx = tid + it * BLOCK;
        const int c = idx >> 5, p = idx & 31;
        pf[it] = *reinterpret_cast<const float4*>(
            feat + ((size_t)(b*C_ + c) * N_ + (n0 + p)) * K_);
    }
    float rl[6];
    if (tid < 96) {
        const int p = tid & 31, k = tid >> 5, n = n0 + p;
        rl[0] = src[((size_t)(b*3+0)*N_ + n)*K_ + k];
        rl[1] = src[((size_t)(b*3+1)*N_ + n)*K_ + k];
        rl[2] = src[((size_t)(b*3+2)*N_ + n)*K_ + k];
        rl[3] = tgt[(size_t)(b*3+0)*N_ + n];
        rl[4] = tgt[(size_t)(b*3+1)*N_ + n];
        rl[5] = tgt[(size_t)(b*3+2)*N_ + n];
    }
    // zero pads while loads fly: fr8 pos4..7 and all of fr9
    if (tid < 96) {
        *reinterpret_cast<short4v*>(&xa[(8*96 + tid)*8 + 4]) = short4v{0,0,0,0};
        *reinterpret_cast<short8*>(&xa[(9*96 + tid)*8])      = short8{0,0,0,0,0,0,0,0};
    }
    // convert + write feature -> frs 0..7 (+ fr8 pos 0..3 from relation below)
#pragma unroll
    for (int it = 0; it < 4; ++it) {
        const int idx = tid + it * BLOCK;
        const int c = idx >> 5, p = idx & 31;
        const float v[3] = {pf[it].x, pf[it].y, pf[it].z};
#pragma unroll
        for (int k = 0; k < 3; ++k)
            xa[((c >> 3)*96 + k*32 + p)*8 + (c & 7)] = (unsigned short)f16bits(v[k]);
    }
    if (tid < 96) {
        const int p = tid & 31, k = tid >> 5;
        const float d0 = rl[0]-rl[3], d1 = rl[1]-rl[4], d2 = rl[2]-rl[5];
        const float d[4] = {d0, d1, d2, d0*d0 + d1*d1 + d2*d2};
        const int base = (8*96 + k*32 + p)*8;
#pragma unroll
        for (int j = 0; j < 4; ++j)
            xa[base + j] = (unsigned short)f16bits(d[j]);
    }
    __syncthreads();

    // coalesced dump: 960 short8s
    short8* dst = reinterpret_cast<short8*>(xg + (size_t)blockIdx.x * XG_SHORTS);
    const short8* srcv = reinterpret_cast<const short8*>(xa);
    for (int i = tid; i < XG_SHORTS/8; i += BLOCK) dst[i] = srcv[i];
}

// ================= K2: MLP from x-fragment stream ===========================
__global__ __launch_bounds__(BLOCK, 8)
void mvp_mlp(const unsigned short* __restrict__ xg,
             const unsigned short* __restrict__ wf,
             float* __restrict__ out)
{
    __shared__ __align__(16) unsigned short h1f[16*768];   // 24.58 KB
    __shared__ __align__(16) unsigned short h2f[6208];     // 12.42 KB
    // total 37 KB -> 4 blocks/CU at (512,8)

    const int tid = threadIdx.x;
    const int w   = tid >> 6;
    const int l   = tid & 63;
    const int b   = blockIdx.x >> 10;
    const int n0  = (blockIdx.x & 1023) << 5;

    const unsigned short* xb = xg + (size_t)blockIdx.x * XG_SHORTS;

    const int hi32 = l >> 5, c32 = l & 31;
    const int lq = l >> 4, lr = l & 15, rq = lq << 2;
    const float* fb = reinterpret_cast<const float*>(wf + BIAS_OFF);

    // ---- L1: 68 -> 128 (f16 32x32, 12 tiles); B-frags straight from global --
    {
        const int npass = (w < 4) ? 2 : 1;
        for (int pass = 0; pass < npass; ++pass) {
            const int t = pass ? (8 + w) : w;
            const int m = t / 3, n = t % 3;
            const int col = n*32 + c32;
            half8 ah[5];
#pragma unroll
            for (int ks = 0; ks < 5; ++ks) ah[ks] = ldfrag(wf, m*5 + ks, l);
            f32x16 acc;
#pragma unroll
            for (int j = 0; j < 16; ++j) acc[j] = 0.0f;
#pragma unroll
            for (int ks = 0; ks < 5; ++ks) {     // ks=4 hits frs 8,9 (9 = zeros)
                const int so = ((ks*2 + hi32)*96 + col)*8;
                const half8 bh = __builtin_bit_cast(half8,
                    *reinterpret_cast<const short8*>(&xb[so]));
                acc = mm32h(ah[ks], bh, acc);
            }
#pragma unroll
            for (int g = 0; g < 4; ++g) {
                const int co0 = m*32 + 8*g + 4*hi32;
                const float4 bb = *reinterpret_cast<const float4*>(fb + co0);
                const float bbv[4] = {bb.x, bb.y, bb.z, bb.w};
                short4v h4;
#pragma unroll
                for (int r = 0; r < 4; ++r)
                    h4[r] = f16bits(fmaxf(acc[g*4 + r] + bbv[r], 0.0f));
                const int so = ((m*4 + g)*96 + col)*8 + 4*hi32;
                *reinterpret_cast<short4v*>(&h1f[so]) = h4;
            }
        }
    }
    __syncthreads();

    // ---- L2: 128 -> 64 (f16 32x32, 6 tiles, waves 0..5) ----
    if (w < 6) {
        const int m = w / 3, n = w % 3;
        const int col = n*32 + c32;
        f32x16 acc;
#pragma unroll
        for (int j = 0; j < 16; ++j) acc[j] = 0.0f;
#pragma unroll
        for (int ks = 0; ks < 8; ++ks) {
            const half8 ah = ldfrag(wf, 20 + m*8 + ks, l);
            const int so = ((ks*2 + hi32)*96 + col)*8;
            const half8 bh = __builtin_bit_cast(half8,
                *reinterpret_cast<const short8*>(&h1f[so]));
            acc = mm32h(ah, bh, acc);
        }
#pragma unroll
        for (int g = 0; g < 4; ++g) {
            const int co0 = m*32 + 8*g + 4*hi32;
            const float4 bb = *reinterpret_cast<const float4*>(fb + 128 + co0);
            const float bbv[4] = {bb.x, bb.y, bb.z, bb.w};
            short4v h4;
#pragma unroll
            for (int r = 0; r < 4; ++r)
                h4[r] = f16bits(fmaxf(acc[g*4 + r] + bbv[r], 0.0f));
            const int so = (m*4 + g)*H2STR + col*8 + 4*hi32;
            *reinterpret_cast<short4v*>(&h2f[so]) = h4;
        }
    }
    __syncthreads();

    // ---- L3: 64 -> 64 (f16 16x16), relu + neighbor-sum + store ----
    {
        const int m = w >> 1, hh = w & 1;
        half8 ah[2];
#pragma unroll
        for (int ks = 0; ks < 2; ++ks) ah[ks] = ldfrag(wf, 36 + m*2 + ks, l);
        f32x4 acc3[3] = {f32x4{0,0,0,0}, f32x4{0,0,0,0}, f32x4{0,0,0,0}};
#pragma unroll
        for (int ks = 0; ks < 2; ++ks) {
#pragma unroll
            for (int t = 0; t < 3; ++t) {
                const int so = (ks*4 + lq)*H2STR + (t*32 + hh*16 + lr)*8;
                const half8 bh = __builtin_bit_cast(half8,
                    *reinterpret_cast<const short8*>(&h2f[so]));
                acc3[t] = mm16h(ah[ks], bh, acc3[t]);
            }
        }
        const int co0 = m*16 + rq;
        const float4 bb = *reinterpret_cast<const float4*>(fb + 192 + co0);
        const float bbv[4] = {bb.x, bb.y, bb.z, bb.w};
#pragma unroll
        for (int r = 0; r < 4; ++r) {
            float s = 0.0f;
#pragma unroll
            for (int t = 0; t < 3; ++t) s += fmaxf(acc3[t][r] + bbv[r], 0.0f);
            out[(size_t)(b*64 + co0 + r) * N_ + n0 + hh*16 + lr] = s;
        }
    }
}

// ================= fallback: R17 single kernel (137.6 us, proven) ===========
__global__ __launch_bounds__(BLOCK, 8)
void mvp_mfma(const float* __restrict__ src, const float* __restrict__ tgt,
              const float* __restrict__ feat,
              const unsigned short* __restrict__ wf,
              float* __restrict__ out)
{
    __shared__ __align__(16) unsigned short xa[XSZ];
    __shared__ __align__(16) unsigned short h1f[16*768];

    const int tid = threadIdx.x;
    const int w   = tid >> 6;
    const int l   = tid & 63;
    const int b   = blockIdx.x >> 10;
    const int n0  = (blockIdx.x & 1023) << 5;

    unsigned short* h2f = xa;

    float4 pf[4];
#pragma unroll
    for (int it = 0; it < 4; ++it) {
        const int idx = tid + it * BLOCK;
        const int c = idx >> 5, p = idx & 31;
        pf[it] = *reinterpret_cast<const float4*>(
            feat + ((size_t)(b*C_ + c) * N_ + (n0 + p)) * K_);
    }
    float rl[6];
    if (tid < 96) {
        const int p = tid & 31, k = tid >> 5, n = n0 + p;
        rl[0] = src[((size_t)(b*3+0)*N_ + n)*K_ + k];
        rl[1] = src[((size_t)(b*3+1)*N_ + n)*K_ + k];
        rl[2] = src[((size_t)(b*3+2)*N_ + n)*K_ + k];
        rl[3] = tgt[(size_t)(b*3+0)*N_ + n];
        rl[4] = tgt[(size_t)(b*3+1)*N_ + n];
        rl[5] = tgt[(size_t)(b*3+2)*N_ + n];
    }
    if (tid < 96) {
        const int o = (8*96 + tid) * 8 + 4;
        *reinterpret_cast<short4v*>(&xa[o]) = short4v{0,0,0,0};
    } else if (tid == 96) {
        *reinterpret_cast<short8*>(xa + ZOFF) = short8{0,0,0,0,0,0,0,0};
    }
#pragma unroll
    for (int it = 0; it < 4; ++it) {
        const int idx = tid + it * BLOCK;
        const int c = idx >> 5, p = idx & 31;
        const float v[3] = {pf[it].x, pf[it].y, pf[it].z};
#pragma unroll
        for (int k = 0; k < 3; ++k)
            xa[((c >> 3)*96 + k*32 + p)*8 + (c & 7)] = (unsigned short)f16bits(v[k]);
    }
    if (tid < 96) {
        const int p = tid & 31, k = tid >> 5;
        const float d0 = rl[0]-rl[3], d1 = rl[1]-rl[4], d2 = rl[2]-rl[5];
        const float d[4] = {d0, d1, d2, d0*d0 + d1*d1 + d2*d2};
        const int base = (8*96 + k*32 + p)*8;
#pragma unroll
        for (int j = 0; j < 4; ++j)
            xa[base + j] = (unsigned short)f16bits(d[j]);
    }
    __syncthreads();

    const int hi32 = l >> 5, c32 = l & 31;
    const int lq = l >> 4, lr = l & 15, rq = lq << 2;
    const float* fb = reinterpret_cast<const float*>(wf + BIAS_OFF);

    {
        const int npass = (w < 4) ? 2 : 1;
        for (int pass = 0; pass < npass; ++pass) {
            const int t = pass ? (8 + w) : w;
            const int m = t / 3, n = t % 3;
            const int col = n*32 + c32;
            half8 ah[5];
#pragma unroll
            for (int ks = 0; ks < 5; ++ks) ah[ks] = ldfrag(wf, m*5 + ks, l);
            f32x16 acc;
#pragma unroll
            for (int j = 0; j < 16; ++j) acc[j] = 0.0f;
#pragma unroll
            for (int ks = 0; ks < 4; ++ks) {
                const int so = ((ks*2 + hi32)*96 + col)*8;
                const half8 bh = __builtin_bit_cast(half8,
                    *reinterpret_cast<const short8*>(&xa[so]));
                acc = mm32h(ah[ks], bh, acc);
            }
            {
                const int so = hi32 ? ZOFF : (8*96 + col)*8;
                const half8 bh = __builtin_bit_cast(half8,
                    *reinterpret_cast<const short8*>(&xa[so]));
                acc = mm32h(ah[4], bh, acc);
            }
#pragma unroll
            for (int g = 0; g < 4; ++g) {
                const int co0 = m*32 + 8*g + 4*hi32;
                const float4 bb = *reinterpret_cast<const float4*>(fb + co0);
                const float bbv[4] = {bb.x, bb.y, bb.z, bb.w};
                short4v h4;
#pragma unroll
                for (int r = 0; r < 4; ++r)
                    h4[r] = f16bits(fmaxf(acc[g*4 + r] + bbv[r], 0.0f));
                const int so = ((m*4 + g)*96 + col)*8 + 4*hi32;
                *reinterpret_cast<short4v*>(&h1f[so]) = h4;
            }
        }
    }
    __syncthreads();

    if (w < 6) {
        const int m = w / 3, n = w % 3;
        const int col = n*32 + c32;
        f32x16 acc;
#pragma unroll
        for (int j = 0; j < 16; ++j) acc[j] = 0.0f;
#pragma unroll
        for (int ks = 0; ks < 8; ++ks) {
            const half8 ah = ldfrag(wf, 20 + m*8 + ks, l);
            const int so = ((ks*2 + hi32)*96 + col)*8;
            const half8 bh = __builtin_bit_cast(half8,
                *reinterpret_cast<const short8*>(&h1f[so]));
            acc = mm32h(ah, bh, acc);
        }
#pragma unroll
        for (int g = 0; g < 4; ++g) {
            const int co0 = m*32 + 8*g + 4*hi32;
            const float4 bb = *reinterpret_cast<const float4*>(fb + 128 + co0);
            const float bbv[4] = {bb.x, bb.y, bb.z, bb.w};
            short4v h4;
#pragma unroll
            for (int r = 0; r < 4; ++r)
                h4[r] = f16bits(fmaxf(acc[g*4 + r] + bbv[r], 0.0f));
            const int so = (m*4 + g)*H2STR + col*8 + 4*hi32;
            *reinterpret_cast<short4v*>(&h2f[so]) = h4;
        }
    }
    __syncthreads();

    {
        const int m = w >> 1, hh = w & 1;
        half8 ah[2];
#pragma unroll
        for (int ks = 0; ks < 2; ++ks) ah[ks] = ldfrag(wf, 36 + m*2 + ks, l);
        f32x4 acc3[3] = {f32x4{0,0,0,0}, f32x4{0,0,0,0}, f32x4{0,0,0,0}};
#pragma unroll
        for (int ks = 0; ks < 2; ++ks) {
#pragma unroll
            for (int t = 0; t < 3; ++t) {
                const int so = (ks*4 + lq)*H2STR + (t*32 + hh*16 + lr)*8;
                const half8 bh = __builtin_bit_cast(half8,
                    *reinterpret_cast<const short8*>(&h2f[so]));
                acc3[t] = mm16h(ah[ks], bh, acc3[t]);
            }
        }
        const int co0 = m*16 + rq;
        const float4 bb = *reinterpret_cast<const float4*>(fb + 192 + co0);
        const float bbv[4] = {bb.x, bb.y, bb.z, bb.w};
#pragma unroll
        for (int r = 0; r < 4; ++r) {
            float s = 0.0f;
#pragma unroll
            for (int t = 0; t < 3; ++t) s += fmaxf(acc3[t][r] + bbv[r], 0.0f);
            out[(size_t)(b*64 + co0 + r) * N_ + n0 + hh*16 + lr] = s;
        }
    }
}

extern "C" void kernel_launch(void* const* d_in, const int* in_sizes, int n_in,
                              void* d_out, int out_size, void* d_ws, size_t ws_size,
                              hipStream_t stream) {
    const float* src  = (const float*)d_in[0];
    const float* tgt  = (const float*)d_in[1];
    const float* feat = (const float*)d_in[2];
    const float* W1 = (const float*)d_in[3];
    const float* b1 = (const float*)d_in[4];
    const float* g1 = (const float*)d_in[5];
    const float* be1= (const float*)d_in[6];
    const float* W2 = (const float*)d_in[7];
    const float* b2 = (const float*)d_in[8];
    const float* g2 = (const float*)d_in[9];
    const float* be2= (const float*)d_in[10];
    const float* W3 = (const float*)d_in[11];
    const float* b3 = (const float*)d_in[12];
    const float* g3 = (const float*)d_in[13];
    const float* be3= (const float*)d_in[14];
    float* out = (float*)d_out;
    unsigned short* wfrag = (unsigned short*)d_ws;

    prep_wfrags<<<12, 256, 0, stream>>>(W1, g1, b1, be1, W2, g2, b2, be2,
                                        W3, g3, b3, be3, wfrag);

    const size_t need = XG_OFF + (size_t)NBLK * XG_SHORTS * 2;
    if (ws_size >= need) {
        unsigned short* xg = (unsigned short*)((char*)d_ws + XG_OFF);
        prep_x<<<NBLK, BLOCK, 0, stream>>>(src, tgt, feat, xg);
        mvp_mlp<<<NBLK, BLOCK, 0, stream>>>(xg, wfrag, out);
    } else {
        mvp_mfma<<<NBLK, BLOCK, 0, stream>>>(src, tgt, feat, wfrag, out);
    }
}